// Round 1
// baseline (127.412 us; speedup 1.0000x reference)
//
#include <hip/hip_runtime.h>
#include <hip/hip_bf16.h>
#include <stdint.h>

#define S_LEN 2048
#define DMODEL 1024
#define NHEAD 16
#define HDIM 64
#define BATCH 2
#define MROWS (BATCH * S_LEN) /* 4096 */

typedef unsigned short u16;
typedef __attribute__((ext_vector_type(8))) short bf16x8;
typedef __attribute__((ext_vector_type(4))) float f32x4;

__device__ inline u16 f32_to_bf16(float f) {
  union { float f; unsigned int u; } v; v.f = f;
  unsigned int u = v.u;
  unsigned int r = (u + 0x7fffu + ((u >> 16) & 1u)) >> 16;
  return (u16)r;
}

__device__ inline void gload16(const u16* g, u16* l) {
  __builtin_amdgcn_global_load_lds(
      (const __attribute__((address_space(1))) unsigned int*)g,
      (__attribute__((address_space(3))) unsigned int*)l, 16, 0, 0);
}

// ---------------- window-size kernel (1 block) ----------------
__global__ void win_kernel(const float* __restrict__ x, const float* __restrict__ alpha,
                           int* __restrict__ halfw) {
  __shared__ float red[4];
  int tid = threadIdx.x;
  float s = 0.f;
  for (int i = tid; i < BATCH * DMODEL; i += 256) {
    int b = i >> 10, d = i & 1023;
    size_t base = (size_t)b * S_LEN * DMODEL + d;
    float f1 = x[base + (size_t)(S_LEN - 1) * DMODEL];
    float f0 = x[base + (size_t)(S_LEN - 2) * DMODEL];
    s += fabsf(f1 - f0);
  }
#pragma unroll
  for (int m = 32; m >= 1; m >>= 1) s += __shfl_xor(s, m, 64);
  if ((tid & 63) == 0) red[tid >> 6] = s;
  __syncthreads();
  if (tid == 0) {
    float total = red[0] + red[1] + red[2] + red[3];
    float mean = total / (float)(BATCH * DMODEL);
    float e1 = x[(size_t)(S_LEN - 1) * DMODEL];
    float e0 = x[(size_t)(S_LEN - 2) * DMODEL];
    float ew = fabsf(e1 - e0);
    float a = 1.f / (1.f + expf(-alpha[0]));
    float sig = a * mean + (1.f - a) * ew;
    float scale = 1.f / (1.f + expf(-sig));
    int wv = (int)floorf(24.f + 96.f * scale);
    *halfw = wv >> 1;
  }
}

// ---------------- x -> bf16 ----------------
__global__ __launch_bounds__(256) void conv_x_bf16(const float* __restrict__ x,
                                                   u16* __restrict__ xb) {
  size_t i = ((size_t)blockIdx.x * 256 + threadIdx.x) * 8;
  float4 v0 = *(const float4*)(x + i);
  float4 v1 = *(const float4*)(x + i + 4);
  bf16x8 r;
  r[0] = (short)f32_to_bf16(v0.x); r[1] = (short)f32_to_bf16(v0.y);
  r[2] = (short)f32_to_bf16(v0.z); r[3] = (short)f32_to_bf16(v0.w);
  r[4] = (short)f32_to_bf16(v1.x); r[5] = (short)f32_to_bf16(v1.y);
  r[6] = (short)f32_to_bf16(v1.z); r[7] = (short)f32_to_bf16(v1.w);
  *(bf16x8*)(xb + i) = r;
}

// ---------------- transpose Wq/Wk/Wv -> bf16 [3][N][K] ----------------
__global__ __launch_bounds__(256) void transpose_qkv(const float* __restrict__ Wq,
                                                     const float* __restrict__ Wk,
                                                     const float* __restrict__ Wv,
                                                     u16* __restrict__ Wt) {
  __shared__ float tile[32][33];
  const float* W = blockIdx.z == 0 ? Wq : (blockIdx.z == 1 ? Wk : Wv);
  int k0 = blockIdx.x * 32, n0 = blockIdx.y * 32;
  int tx = threadIdx.x, ty = threadIdx.y; // (32, 8)
#pragma unroll
  for (int i = 0; i < 4; ++i)
    tile[ty + i * 8][tx] = W[(size_t)(k0 + ty + i * 8) * DMODEL + n0 + tx];
  __syncthreads();
  u16* o = Wt + (size_t)blockIdx.z * DMODEL * DMODEL;
#pragma unroll
  for (int i = 0; i < 4; ++i)
    o[(size_t)(n0 + ty + i * 8) * DMODEL + k0 + tx] = f32_to_bf16(tile[tx][ty + i * 8]);
}

// ---------------- Wc = blockdiag(W_o) @ Wfc, stored transposed bf16 [N][K] ----------------
__global__ __launch_bounds__(128) void build_wc(const float* __restrict__ W_o,
                                                const float* __restrict__ Wfc,
                                                u16* __restrict__ Wc_t) {
  __shared__ float lds[64 * 128];
  int nb = blockIdx.x, h = blockIdx.y, tx = threadIdx.x;
  int n0 = nb * 128;
#pragma unroll
  for (int c = 0; c < 64; ++c)
    lds[c * 128 + tx] = Wfc[(size_t)(h * 64 + c) * DMODEL + n0 + tx];
  __syncthreads();
  float acc[64];
#pragma unroll
  for (int d = 0; d < 64; ++d) acc[d] = 0.f;
  for (int c = 0; c < 64; ++c) {
    float wv = lds[c * 128 + tx];
#pragma unroll
    for (int d = 0; d < 64; ++d)
      acc[d] += W_o[(size_t)(h * 64 + d) * 64 + c] * wv;
  }
  u16 tmp[64];
#pragma unroll
  for (int d = 0; d < 64; ++d) tmp[d] = f32_to_bf16(acc[d]);
  u16* dst = Wc_t + (size_t)(n0 + tx) * DMODEL + h * 64;
#pragma unroll
  for (int q = 0; q < 8; ++q)
    *(bf16x8*)(dst + q * 8) = *(bf16x8*)(tmp + q * 8);
}

// ---------------- GEMM: C[M,N] = A[M,K] @ Bt[N,K]^T + bias ----------------
// 128x128 tile, BK=64, 4 waves (2x2), each wave 64x64 via 4x4 16x16x32 MFMA.
// global_load_lds w/ pre-swizzled source; XOR-swizzled ds_read (T2, rule 21).
template <int BF16_OUT>
__global__ __launch_bounds__(256) void gemm_bt(
    const u16* __restrict__ A, const u16* __restrict__ Bt,
    const float* __restrict__ bias0, const float* __restrict__ bias1,
    const float* __restrict__ bias2,
    void* __restrict__ out0, void* __restrict__ out1, void* __restrict__ out2,
    int K) {
  __shared__ __align__(16) u16 smem[128 * 64 * 2];
  u16* As = smem;
  u16* Bs = smem + 128 * 64;

  const int tid = threadIdx.x;
  const int l = tid & 63, w = tid >> 6;
  const int wr = w >> 1, wc = w & 1;
  const int lrow = l & 15, lk = l >> 4;
  const int bm = blockIdx.x, bn = blockIdx.y;
  const int rowA0 = bm * 128, rowB0 = bn * 128;

  f32x4 acc[4][4] = {};

  for (int kt = 0; kt < K; kt += 64) {
    __syncthreads();
#pragma unroll
    for (int i = 0; i < 4; ++i) {
      int c_lin = i * 256 + tid;
      int row = c_lin >> 3, u = c_lin & 7;
      const u16* g = A + (size_t)(rowA0 + row) * K + kt + ((u ^ (row & 7)) << 3);
      gload16(g, As + (i * 2048 + w * 512));
    }
#pragma unroll
    for (int i = 0; i < 4; ++i) {
      int c_lin = i * 256 + tid;
      int row = c_lin >> 3, u = c_lin & 7;
      const u16* g = Bt + (size_t)(rowB0 + row) * K + kt + ((u ^ (row & 7)) << 3);
      gload16(g, Bs + (i * 2048 + w * 512));
    }
    asm volatile("s_waitcnt vmcnt(0)");
    __syncthreads();
#pragma unroll
    for (int kk = 0; kk < 2; ++kk) {
      bf16x8 af[4], bg[4];
#pragma unroll
      for (int m = 0; m < 4; ++m) {
        int r = wr * 64 + m * 16 + lrow;
        af[m] = *(const bf16x8*)(As + r * 64 + ((((kk << 2) + lk) ^ (lrow & 7)) << 3));
      }
#pragma unroll
      for (int n = 0; n < 4; ++n) {
        int r = wc * 64 + n * 16 + lrow;
        bg[n] = *(const bf16x8*)(Bs + r * 64 + ((((kk << 2) + lk) ^ (lrow & 7)) << 3));
      }
#pragma unroll
      for (int m = 0; m < 4; ++m)
#pragma unroll
        for (int n = 0; n < 4; ++n)
          acc[m][n] = __builtin_amdgcn_mfma_f32_16x16x32_bf16(af[m], bg[n], acc[m][n], 0, 0, 0);
    }
  }

  const int sub = rowB0 >> 10;
  const float* bias = sub == 0 ? bias0 : (sub == 1 ? bias1 : bias2);
  void* outp = sub == 0 ? out0 : (sub == 1 ? out1 : out2);
  const int orow0 = rowA0 + wr * 64;
  const int ocol0 = (rowB0 & 1023) + wc * 64;
#pragma unroll
  for (int m = 0; m < 4; ++m)
#pragma unroll
    for (int n = 0; n < 4; ++n) {
      int c = ocol0 + n * 16 + lrow;
      float bv = bias[c];
#pragma unroll
      for (int j = 0; j < 4; ++j) {
        int r = orow0 + m * 16 + lk * 4 + j;
        float v = acc[m][n][j] + bv;
        if (BF16_OUT)
          ((u16*)outp)[(size_t)r * DMODEL + c] = f32_to_bf16(v);
        else
          ((float*)outp)[(size_t)r * DMODEL + c] = v;
      }
    }
}

// ---------------- banded attention: 64 queries x 192 keys per block ----------------
__global__ __launch_bounds__(256) void attn_win(const u16* __restrict__ qb,
                                                const u16* __restrict__ kb,
                                                const u16* __restrict__ vb,
                                                u16* __restrict__ ao,
                                                const int* __restrict__ halfptr) {
  __shared__ __align__(16) u16 KsPs[192 * 72]; // K tile [key][d], later reused as P [64][200]
  __shared__ __align__(16) u16 Vt[64 * 200];   // V transposed [d][key]
  const int tid = threadIdx.x, l = tid & 63, w = tid >> 6;
  const int lrow = l & 15, lk = l >> 4;
  const int qb_i = blockIdx.x, h = blockIdx.y, b = blockIdx.z;
  const int q0 = qb_i * 64, k0 = q0 - 64;
  const int halfw = *halfptr;

  const bf16x8 zero = {0, 0, 0, 0, 0, 0, 0, 0};
  // stage K: 192 rows x 64 d  (rows padded to 72 elems = 144B)
#pragma unroll
  for (int i = 0; i < 6; ++i) {
    int c = i * 256 + tid; // 0..1535
    int row = c >> 3, ch = c & 7;
    int key = k0 + row;
    bf16x8 v = zero;
    if (key >= 0 && key < S_LEN)
      v = *(const bf16x8*)(kb + (size_t)(b * S_LEN + key) * DMODEL + h * 64 + ch * 8);
    *(bf16x8*)(KsPs + row * 72 + ch * 8) = v;
  }
  // stage V transposed: Vt[d][key], row-major stride 200
#pragma unroll
  for (int i = 0; i < 6; ++i) {
    int c = i * 256 + tid;
    int row = c % 192, ch = c / 192;
    int key = k0 + row;
    bf16x8 v = zero;
    if (key >= 0 && key < S_LEN)
      v = *(const bf16x8*)(vb + (size_t)(b * S_LEN + key) * DMODEL + h * 64 + ch * 8);
#pragma unroll
    for (int e = 0; e < 8; ++e)
      Vt[(ch * 8 + e) * 200 + row] = (u16)v[e];
  }
  // Q fragments straight from global (each wave: 16 query rows)
  const int qrow = q0 + w * 16 + lrow;
  bf16x8 qf[2];
#pragma unroll
  for (int kk = 0; kk < 2; ++kk)
    qf[kk] = *(const bf16x8*)(qb + (size_t)(b * S_LEN + qrow) * DMODEL + h * 64 + kk * 32 + lk * 8);

  __syncthreads();

  // QK^T -> 16 x 192 per wave (12 col-fragments)
  f32x4 sc[12];
#pragma unroll
  for (int f = 0; f < 12; ++f) sc[f] = (f32x4){0.f, 0.f, 0.f, 0.f};
#pragma unroll
  for (int kk = 0; kk < 2; ++kk) {
#pragma unroll
    for (int f = 0; f < 12; ++f) {
      bf16x8 kf = *(const bf16x8*)(KsPs + (f * 16 + lrow) * 72 + kk * 32 + lk * 8);
      sc[f] = __builtin_amdgcn_mfma_f32_16x16x32_bf16(qf[kk], kf, sc[f], 0, 0, 0);
    }
  }
  // mask + row max
  float rmax[4] = {-3e38f, -3e38f, -3e38f, -3e38f};
  const int qbase = q0 + w * 16 + lk * 4;
#pragma unroll
  for (int f = 0; f < 12; ++f) {
    int kj = k0 + f * 16 + lrow;
    bool kok = (kj >= 0) && (kj < S_LEN);
#pragma unroll
    for (int j = 0; j < 4; ++j) {
      int qi = qbase + j;
      float v = sc[f][j] * 0.125f;
      int dd = qi - kj;
      int ad = dd < 0 ? -dd : dd;
      v = (kok && ad <= halfw) ? v : -1e30f;
      sc[f][j] = v;
      rmax[j] = fmaxf(rmax[j], v);
    }
  }
#pragma unroll
  for (int j = 0; j < 4; ++j) {
    rmax[j] = fmaxf(rmax[j], __shfl_xor(rmax[j], 1, 16));
    rmax[j] = fmaxf(rmax[j], __shfl_xor(rmax[j], 2, 16));
    rmax[j] = fmaxf(rmax[j], __shfl_xor(rmax[j], 4, 16));
    rmax[j] = fmaxf(rmax[j], __shfl_xor(rmax[j], 8, 16));
  }
  float rsum[4] = {0.f, 0.f, 0.f, 0.f};
#pragma unroll
  for (int f = 0; f < 12; ++f)
#pragma unroll
    for (int j = 0; j < 4; ++j) {
      float e = __expf(sc[f][j] - rmax[j]);
      sc[f][j] = e;
      rsum[j] += e;
    }
#pragma unroll
  for (int j = 0; j < 4; ++j) {
    rsum[j] += __shfl_xor(rsum[j], 1, 16);
    rsum[j] += __shfl_xor(rsum[j], 2, 16);
    rsum[j] += __shfl_xor(rsum[j], 4, 16);
    rsum[j] += __shfl_xor(rsum[j], 8, 16);
  }
  float rinv[4];
#pragma unroll
  for (int j = 0; j < 4; ++j) rinv[j] = 1.0f / rsum[j];

  __syncthreads(); // all K reads done before P overwrites the same LDS

  u16* Ps = KsPs; // P tile [64][200]
#pragma unroll
  for (int f = 0; f < 12; ++f)
#pragma unroll
    for (int j = 0; j < 4; ++j) {
      int prow = w * 16 + lk * 4 + j;
      Ps[prow * 200 + f * 16 + lrow] = f32_to_bf16(sc[f][j] * rinv[j]);
    }
  __syncthreads();

  // P @ V : 16 x 64 per wave
  f32x4 o[4] = {};
#pragma unroll
  for (int jt = 0; jt < 6; ++jt) {
    bf16x8 pa = *(const bf16x8*)(Ps + (w * 16 + lrow) * 200 + jt * 32 + lk * 8);
#pragma unroll
    for (int n = 0; n < 4; ++n) {
      bf16x8 vf = *(const bf16x8*)(Vt + (n * 16 + lrow) * 200 + jt * 32 + lk * 8);
      o[n] = __builtin_amdgcn_mfma_f32_16x16x32_bf16(pa, vf, o[n], 0, 0, 0);
    }
  }
#pragma unroll
  for (int n = 0; n < 4; ++n)
#pragma unroll
    for (int j = 0; j < 4; ++j) {
      int qi = q0 + w * 16 + lk * 4 + j;
      int d = n * 16 + lrow;
      ao[(size_t)(b * S_LEN + qi) * DMODEL + h * 64 + d] = f32_to_bf16(o[n][j]);
    }
}

// ---------------- launch ----------------
extern "C" void kernel_launch(void* const* d_in, const int* in_sizes, int n_in,
                              void* d_out, int out_size, void* d_ws, size_t ws_size,
                              hipStream_t stream) {
  (void)in_sizes; (void)n_in; (void)out_size; (void)ws_size;
  const float* x     = (const float*)d_in[0];
  const float* alpha = (const float*)d_in[1];
  const float* Wq    = (const float*)d_in[2];
  const float* bq    = (const float*)d_in[3];
  const float* Wk    = (const float*)d_in[4];
  const float* bk    = (const float*)d_in[5];
  const float* Wv    = (const float*)d_in[6];
  const float* bv    = (const float*)d_in[7];
  const float* W_o   = (const float*)d_in[8];
  const float* Wfc   = (const float*)d_in[9];
  const float* bfc   = (const float*)d_in[10];

  char* ws = (char*)d_ws;
  int* halfw  = (int*)ws;
  u16* xb     = (u16*)(ws + 256);
  u16* Wqkv_t = xb + (size_t)MROWS * DMODEL;
  u16* qb     = Wqkv_t + (size_t)3 * DMODEL * DMODEL;
  u16* kb     = qb + (size_t)MROWS * DMODEL;
  u16* vb     = kb + (size_t)MROWS * DMODEL;
  u16* ao     = vb + (size_t)MROWS * DMODEL;
  u16* Wc_t   = ao + (size_t)MROWS * DMODEL;

  hipLaunchKernelGGL(win_kernel, dim3(1), dim3(256), 0, stream, x, alpha, halfw);
  hipLaunchKernelGGL(conv_x_bf16, dim3(MROWS * DMODEL / (256 * 8)), dim3(256), 0, stream, x, xb);
  hipLaunchKernelGGL(transpose_qkv, dim3(32, 32, 3), dim3(32, 8), 0, stream, Wq, Wk, Wv, Wqkv_t);
  hipLaunchKernelGGL(build_wc, dim3(8, 16), dim3(128), 0, stream, W_o, Wfc, Wc_t);
  hipLaunchKernelGGL((gemm_bt<1>), dim3(32, 24), dim3(256), 0, stream,
                     xb, Wqkv_t, bq, bk, bv, (void*)qb, (void*)kb, (void*)vb, DMODEL);
  hipLaunchKernelGGL(attn_win, dim3(S_LEN / 64, NHEAD, BATCH), dim3(256), 0, stream,
                     qb, kb, vb, ao, halfw);
  hipLaunchKernelGGL((gemm_bt<0>), dim3(32, 8), dim3(256), 0, stream,
                     ao, Wc_t, bfc, bfc, bfc, d_out, d_out, d_out, DMODEL);
}

// Round 2
// 118.230 us; speedup vs baseline: 1.0777x; 1.0777x over previous
//
#include <hip/hip_runtime.h>
#include <hip/hip_bf16.h>
#include <stdint.h>

#define S_LEN 2048
#define DMODEL 1024
#define NHEAD 16
#define HDIM 64
#define BATCH 2
#define MROWS (BATCH * S_LEN) /* 4096 */
#define QKV_LD 3072

typedef unsigned short u16;
typedef __attribute__((ext_vector_type(8))) short bf16x8;
typedef __attribute__((ext_vector_type(4))) float f32x4;

__device__ inline u16 f32_to_bf16(float f) {
  union { float f; unsigned int u; } v; v.f = f;
  unsigned int u = v.u;
  unsigned int r = (u + 0x7fffu + ((u >> 16) & 1u)) >> 16;
  return (u16)r;
}

__device__ inline void gload16(const u16* g, u16* l) {
  __builtin_amdgcn_global_load_lds(
      (const __attribute__((address_space(1))) unsigned int*)g,
      (__attribute__((address_space(3))) unsigned int*)l, 16, 0, 0);
}

// ---------------- window-size kernel (1 block) ----------------
__global__ void win_kernel(const float* __restrict__ x, const float* __restrict__ alpha,
                           int* __restrict__ halfw) {
  __shared__ float red[4];
  int tid = threadIdx.x;
  float s = 0.f;
  for (int i = tid; i < BATCH * DMODEL; i += 256) {
    int b = i >> 10, d = i & 1023;
    size_t base = (size_t)b * S_LEN * DMODEL + d;
    float f1 = x[base + (size_t)(S_LEN - 1) * DMODEL];
    float f0 = x[base + (size_t)(S_LEN - 2) * DMODEL];
    s += fabsf(f1 - f0);
  }
#pragma unroll
  for (int m = 32; m >= 1; m >>= 1) s += __shfl_xor(s, m, 64);
  if ((tid & 63) == 0) red[tid >> 6] = s;
  __syncthreads();
  if (tid == 0) {
    float total = red[0] + red[1] + red[2] + red[3];
    float mean = total / (float)(BATCH * DMODEL);
    float e1 = x[(size_t)(S_LEN - 1) * DMODEL];
    float e0 = x[(size_t)(S_LEN - 2) * DMODEL];
    float ew = fabsf(e1 - e0);
    float a = 1.f / (1.f + expf(-alpha[0]));
    float sig = a * mean + (1.f - a) * ew;
    float scale = 1.f / (1.f + expf(-sig));
    int wv = (int)floorf(24.f + 96.f * scale);
    *halfw = wv >> 1;
  }
}

// ---------------- x -> bf16 ----------------
__global__ __launch_bounds__(256) void conv_x_bf16(const float* __restrict__ x,
                                                   u16* __restrict__ xb) {
  size_t i = ((size_t)blockIdx.x * 256 + threadIdx.x) * 8;
  float4 v0 = *(const float4*)(x + i);
  float4 v1 = *(const float4*)(x + i + 4);
  bf16x8 r;
  r[0] = (short)f32_to_bf16(v0.x); r[1] = (short)f32_to_bf16(v0.y);
  r[2] = (short)f32_to_bf16(v0.z); r[3] = (short)f32_to_bf16(v0.w);
  r[4] = (short)f32_to_bf16(v1.x); r[5] = (short)f32_to_bf16(v1.y);
  r[6] = (short)f32_to_bf16(v1.z); r[7] = (short)f32_to_bf16(v1.w);
  *(bf16x8*)(xb + i) = r;
}

// ---------------- transpose Wq/Wk/Wv -> bf16 [3][N][K] ----------------
__global__ __launch_bounds__(256) void transpose_qkv(const float* __restrict__ Wq,
                                                     const float* __restrict__ Wk,
                                                     const float* __restrict__ Wv,
                                                     u16* __restrict__ Wt) {
  __shared__ float tile[32][33];
  const float* W = blockIdx.z == 0 ? Wq : (blockIdx.z == 1 ? Wk : Wv);
  int k0 = blockIdx.x * 32, n0 = blockIdx.y * 32;
  int tx = threadIdx.x, ty = threadIdx.y; // (32, 8)
#pragma unroll
  for (int i = 0; i < 4; ++i)
    tile[ty + i * 8][tx] = W[(size_t)(k0 + ty + i * 8) * DMODEL + n0 + tx];
  __syncthreads();
  u16* o = Wt + (size_t)blockIdx.z * DMODEL * DMODEL;
#pragma unroll
  for (int i = 0; i < 4; ++i)
    o[(size_t)(n0 + ty + i * 8) * DMODEL + k0 + tx] = f32_to_bf16(tile[tx][ty + i * 8]);
}

// ---------------- Wc = blockdiag(W_o) @ Wfc, stored transposed bf16 [N][K] ----------------
__global__ __launch_bounds__(128) void build_wc(const float* __restrict__ W_o,
                                                const float* __restrict__ Wfc,
                                                u16* __restrict__ Wc_t) {
  __shared__ float lds[64 * 128];
  int nb = blockIdx.x, h = blockIdx.y, tx = threadIdx.x;
  int n0 = nb * 128;
#pragma unroll
  for (int c = 0; c < 64; ++c)
    lds[c * 128 + tx] = Wfc[(size_t)(h * 64 + c) * DMODEL + n0 + tx];
  __syncthreads();
  float acc[64];
#pragma unroll
  for (int d = 0; d < 64; ++d) acc[d] = 0.f;
  for (int c = 0; c < 64; ++c) {
    float wv = lds[c * 128 + tx];
#pragma unroll
    for (int d = 0; d < 64; ++d)
      acc[d] += W_o[(size_t)(h * 64 + d) * 64 + c] * wv;
  }
  u16 tmp[64];
#pragma unroll
  for (int d = 0; d < 64; ++d) tmp[d] = f32_to_bf16(acc[d]);
  u16* dst = Wc_t + (size_t)(n0 + tx) * DMODEL + h * 64;
#pragma unroll
  for (int q = 0; q < 8; ++q)
    *(bf16x8*)(dst + q * 8) = *(bf16x8*)(tmp + q * 8);
}

// ---------------- QKV GEMM: 256x192 tile, BK=64, 8 waves, dbuf 2-phase ----------------
// C[4096][3072] = xb[4096][1024] @ Wqkv_t[3072][1024]^T, bias + q-scale fused.
#define G1_BM 256
#define G1_BN 192
#define G1_ASZ (G1_BM * 64) /* u16 elems */
#define G1_BSZ (G1_BN * 64)
__global__ __launch_bounds__(512, 2) void gemm_qkv(
    const u16* __restrict__ A, const u16* __restrict__ Bt,
    const float* __restrict__ bq, const float* __restrict__ bk,
    const float* __restrict__ bv, u16* __restrict__ out) {
  __shared__ __align__(16) u16 smem[2][G1_ASZ + G1_BSZ]; // 2 x 56 KiB = 112 KiB

  const int tid = threadIdx.x;
  const int l = tid & 63, w = tid >> 6;   // 8 waves
  const int wr = w >> 2, wc = w & 3;      // 2 x 4 wave grid; wave tile 128x48
  const int lrow = l & 15, lk = l >> 4;

  // bijective XCD swizzle (grid 256, 256%8==0): chunk of 32 per XCD, bn-fastest
  const int wgid = (blockIdx.x & 7) * 32 + (blockIdx.x >> 3);
  const int bm = wgid >> 4, bn = wgid & 15;
  const int rowA0 = bm * G1_BM;
  const int colB0 = bn * G1_BN;

  f32x4 acc[8][3] = {};

  // ---- stage(buf, kt) ----
  auto stage = [&](int buf, int kt) {
    u16* As = smem[buf];
    u16* Bs = smem[buf] + G1_ASZ;
#pragma unroll
    for (int i = 0; i < 4; ++i) {
      int c = i * 512 + tid;                 // 2048 chunks of 16B for A
      int row = c >> 3, u = c & 7;
      const u16* g = A + (size_t)(rowA0 + row) * DMODEL + kt + ((u ^ (row & 7)) << 3);
      gload16(g, As + c * 8);
    }
#pragma unroll
    for (int i = 0; i < 3; ++i) {
      int c = i * 512 + tid;                 // 1536 chunks for B
      int row = c >> 3, u = c & 7;
      const u16* g = Bt + (size_t)(colB0 + row) * DMODEL + kt + ((u ^ (row & 7)) << 3);
      gload16(g, Bs + c * 8);
    }
  };

  stage(0, 0);
  asm volatile("s_waitcnt vmcnt(0)");
  __syncthreads();

  int buf = 0;
#pragma unroll 1
  for (int t = 0; t < 16; ++t) {
    if (t < 15) stage(buf ^ 1, (t + 1) * 64);   // prefetch next K-tile
    const u16* As = smem[buf];
    const u16* Bs = smem[buf] + G1_ASZ;
#pragma unroll
    for (int kk = 0; kk < 2; ++kk) {
      bf16x8 af[8], bg[3];
      const int ksw = ((kk << 2) + lk);
#pragma unroll
      for (int m = 0; m < 8; ++m) {
        int r = wr * 128 + m * 16 + lrow;
        af[m] = *(const bf16x8*)(As + r * 64 + ((ksw ^ (lrow & 7)) << 3));
      }
#pragma unroll
      for (int n = 0; n < 3; ++n) {
        int r = wc * 48 + n * 16 + lrow;
        bg[n] = *(const bf16x8*)(Bs + r * 64 + ((ksw ^ (lrow & 7)) << 3));
      }
#pragma unroll
      for (int m = 0; m < 8; ++m)
#pragma unroll
        for (int n = 0; n < 3; ++n)
          acc[m][n] = __builtin_amdgcn_mfma_f32_16x16x32_bf16(af[m], bg[n], acc[m][n], 0, 0, 0);
    }
    if (t < 15) {
      asm volatile("s_waitcnt vmcnt(0)");
      __syncthreads();
      buf ^= 1;
    }
  }

  // ---- epilogue: per-column bias select; q gets *0.125 fold ----
#pragma unroll
  for (int n = 0; n < 3; ++n) {
    int c = colB0 + wc * 48 + n * 16 + lrow;   // 0..3071
    float bias = (c < 1024) ? bq[c] : ((c < 2048) ? bk[c - 1024] : bv[c - 2048]);
    float mult = (c < 1024) ? 0.125f : 1.0f;
#pragma unroll
    for (int m = 0; m < 8; ++m) {
      int r0 = rowA0 + wr * 128 + m * 16 + lk * 4;
#pragma unroll
      for (int j = 0; j < 4; ++j)
        out[(size_t)(r0 + j) * QKV_LD + c] = f32_to_bf16((acc[m][n][j] + bias) * mult);
    }
  }
}

// ---------------- GEMM: C[M,N] = A[M,K] @ Bt[N,K]^T + bias (128^2, f32 out) ----------------
template <int BF16_OUT>
__global__ __launch_bounds__(256) void gemm_bt(
    const u16* __restrict__ A, const u16* __restrict__ Bt,
    const float* __restrict__ bias0, const float* __restrict__ bias1,
    const float* __restrict__ bias2,
    void* __restrict__ out0, void* __restrict__ out1, void* __restrict__ out2,
    int K) {
  __shared__ __align__(16) u16 smem[128 * 64 * 2];
  u16* As = smem;
  u16* Bs = smem + 128 * 64;

  const int tid = threadIdx.x;
  const int l = tid & 63, w = tid >> 6;
  const int wr = w >> 1, wc = w & 1;
  const int lrow = l & 15, lk = l >> 4;
  const int bm = blockIdx.x, bn = blockIdx.y;
  const int rowA0 = bm * 128, rowB0 = bn * 128;

  f32x4 acc[4][4] = {};

  for (int kt = 0; kt < K; kt += 64) {
    __syncthreads();
#pragma unroll
    for (int i = 0; i < 4; ++i) {
      int c_lin = i * 256 + tid;
      int row = c_lin >> 3, u = c_lin & 7;
      const u16* g = A + (size_t)(rowA0 + row) * K + kt + ((u ^ (row & 7)) << 3);
      gload16(g, As + (i * 2048 + w * 512));
    }
#pragma unroll
    for (int i = 0; i < 4; ++i) {
      int c_lin = i * 256 + tid;
      int row = c_lin >> 3, u = c_lin & 7;
      const u16* g = Bt + (size_t)(rowB0 + row) * K + kt + ((u ^ (row & 7)) << 3);
      gload16(g, Bs + (i * 2048 + w * 512));
    }
    asm volatile("s_waitcnt vmcnt(0)");
    __syncthreads();
#pragma unroll
    for (int kk = 0; kk < 2; ++kk) {
      bf16x8 af[4], bg[4];
#pragma unroll
      for (int m = 0; m < 4; ++m) {
        int r = wr * 64 + m * 16 + lrow;
        af[m] = *(const bf16x8*)(As + r * 64 + ((((kk << 2) + lk) ^ (lrow & 7)) << 3));
      }
#pragma unroll
      for (int n = 0; n < 4; ++n) {
        int r = wc * 64 + n * 16 + lrow;
        bg[n] = *(const bf16x8*)(Bs + r * 64 + ((((kk << 2) + lk) ^ (lrow & 7)) << 3));
      }
#pragma unroll
      for (int m = 0; m < 4; ++m)
#pragma unroll
        for (int n = 0; n < 4; ++n)
          acc[m][n] = __builtin_amdgcn_mfma_f32_16x16x32_bf16(af[m], bg[n], acc[m][n], 0, 0, 0);
    }
  }

  const int sub = rowB0 >> 10;
  const float* bias = sub == 0 ? bias0 : (sub == 1 ? bias1 : bias2);
  void* outp = sub == 0 ? out0 : (sub == 1 ? out1 : out2);
  const int orow0 = rowA0 + wr * 64;
  const int ocol0 = (rowB0 & 1023) + wc * 64;
#pragma unroll
  for (int m = 0; m < 4; ++m)
#pragma unroll
    for (int n = 0; n < 4; ++n) {
      int c = ocol0 + n * 16 + lrow;
      float bv = bias[c];
#pragma unroll
      for (int j = 0; j < 4; ++j) {
        int r = orow0 + m * 16 + lk * 4 + j;
        float v = acc[m][n][j] + bv;
        if (BF16_OUT)
          ((u16*)outp)[(size_t)r * DMODEL + c] = f32_to_bf16(v);
        else
          ((float*)outp)[(size_t)r * DMODEL + c] = v;
      }
    }
}

// ---------------- banded attention: 64 queries x 192 keys per block ----------------
__global__ __launch_bounds__(256) void attn_win(const u16* __restrict__ qkv,
                                                u16* __restrict__ ao,
                                                const int* __restrict__ halfptr) {
  __shared__ __align__(16) u16 KsPs[192 * 72]; // K tile [key][d], later reused as P [64][200]
  __shared__ __align__(16) u16 Vt[64 * 200];   // V transposed [d][key]
  const int tid = threadIdx.x, l = tid & 63, w = tid >> 6;
  const int lrow = l & 15, lk = l >> 4;
  const int qb_i = blockIdx.x, h = blockIdx.y, b = blockIdx.z;
  const int q0 = qb_i * 64, k0 = q0 - 64;
  const int halfw = *halfptr;

  const u16* qb = qkv;
  const u16* kb = qkv + 1024;
  const u16* vb = qkv + 2048;

  const bf16x8 zero = {0, 0, 0, 0, 0, 0, 0, 0};
  // stage K: 192 rows x 64 d  (rows padded to 72 elems = 144B)
#pragma unroll
  for (int i = 0; i < 6; ++i) {
    int c = i * 256 + tid; // 0..1535
    int row = c >> 3, ch = c & 7;
    int key = k0 + row;
    bf16x8 v = zero;
    if (key >= 0 && key < S_LEN)
      v = *(const bf16x8*)(kb + (size_t)(b * S_LEN + key) * QKV_LD + h * 64 + ch * 8);
    *(bf16x8*)(KsPs + row * 72 + ch * 8) = v;
  }
  // stage V transposed: Vt[d][key], row-major stride 200
#pragma unroll
  for (int i = 0; i < 6; ++i) {
    int c = i * 256 + tid;
    int row = c % 192, ch = c / 192;
    int key = k0 + row;
    bf16x8 v = zero;
    if (key >= 0 && key < S_LEN)
      v = *(const bf16x8*)(vb + (size_t)(b * S_LEN + key) * QKV_LD + h * 64 + ch * 8);
#pragma unroll
    for (int e = 0; e < 8; ++e)
      Vt[(ch * 8 + e) * 200 + row] = (u16)v[e];
  }
  // Q fragments straight from global (each wave: 16 query rows); q pre-scaled by 0.125
  const int qrow = q0 + w * 16 + lrow;
  bf16x8 qf[2];
#pragma unroll
  for (int kk = 0; kk < 2; ++kk)
    qf[kk] = *(const bf16x8*)(qb + (size_t)(b * S_LEN + qrow) * QKV_LD + h * 64 + kk * 32 + lk * 8);

  __syncthreads();

  // QK^T -> 16 x 192 per wave (12 col-fragments)
  f32x4 sc[12];
#pragma unroll
  for (int f = 0; f < 12; ++f) sc[f] = (f32x4){0.f, 0.f, 0.f, 0.f};
#pragma unroll
  for (int kk = 0; kk < 2; ++kk) {
#pragma unroll
    for (int f = 0; f < 12; ++f) {
      bf16x8 kf = *(const bf16x8*)(KsPs + (f * 16 + lrow) * 72 + kk * 32 + lk * 8);
      sc[f] = __builtin_amdgcn_mfma_f32_16x16x32_bf16(qf[kk], kf, sc[f], 0, 0, 0);
    }
  }
  // mask + row max (scores already scaled via q)
  float rmax[4] = {-3e38f, -3e38f, -3e38f, -3e38f};
  const int qbase = q0 + w * 16 + lk * 4;
#pragma unroll
  for (int f = 0; f < 12; ++f) {
    int kj = k0 + f * 16 + lrow;
    bool kok = (kj >= 0) && (kj < S_LEN);
#pragma unroll
    for (int j = 0; j < 4; ++j) {
      int qi = qbase + j;
      float v = sc[f][j];
      int dd = qi - kj;
      int ad = dd < 0 ? -dd : dd;
      v = (kok && ad <= halfw) ? v : -1e30f;
      sc[f][j] = v;
      rmax[j] = fmaxf(rmax[j], v);
    }
  }
#pragma unroll
  for (int j = 0; j < 4; ++j) {
    rmax[j] = fmaxf(rmax[j], __shfl_xor(rmax[j], 1, 16));
    rmax[j] = fmaxf(rmax[j], __shfl_xor(rmax[j], 2, 16));
    rmax[j] = fmaxf(rmax[j], __shfl_xor(rmax[j], 4, 16));
    rmax[j] = fmaxf(rmax[j], __shfl_xor(rmax[j], 8, 16));
  }
  float rsum[4] = {0.f, 0.f, 0.f, 0.f};
#pragma unroll
  for (int f = 0; f < 12; ++f)
#pragma unroll
    for (int j = 0; j < 4; ++j) {
      float e = __expf(sc[f][j] - rmax[j]);
      sc[f][j] = e;
      rsum[j] += e;
    }
#pragma unroll
  for (int j = 0; j < 4; ++j) {
    rsum[j] += __shfl_xor(rsum[j], 1, 16);
    rsum[j] += __shfl_xor(rsum[j], 2, 16);
    rsum[j] += __shfl_xor(rsum[j], 4, 16);
    rsum[j] += __shfl_xor(rsum[j], 8, 16);
  }
  float rinv[4];
#pragma unroll
  for (int j = 0; j < 4; ++j) rinv[j] = 1.0f / rsum[j];

  __syncthreads(); // all K reads done before P overwrites the same LDS

  u16* Ps = KsPs; // P tile [64][200]
#pragma unroll
  for (int f = 0; f < 12; ++f)
#pragma unroll
    for (int j = 0; j < 4; ++j) {
      int prow = w * 16 + lk * 4 + j;
      Ps[prow * 200 + f * 16 + lrow] = f32_to_bf16(sc[f][j] * rinv[j]);
    }
  __syncthreads();

  // P @ V : 16 x 64 per wave
  f32x4 o[4] = {};
#pragma unroll
  for (int jt = 0; jt < 6; ++jt) {
    bf16x8 pa = *(const bf16x8*)(Ps + (w * 16 + lrow) * 200 + jt * 32 + lk * 8);
#pragma unroll
    for (int n = 0; n < 4; ++n) {
      bf16x8 vf = *(const bf16x8*)(Vt + (n * 16 + lrow) * 200 + jt * 32 + lk * 8);
      o[n] = __builtin_amdgcn_mfma_f32_16x16x32_bf16(pa, vf, o[n], 0, 0, 0);
    }
  }
#pragma unroll
  for (int n = 0; n < 4; ++n)
#pragma unroll
    for (int j = 0; j < 4; ++j) {
      int qi = q0 + w * 16 + lk * 4 + j;
      int d = n * 16 + lrow;
      ao[(size_t)(b * S_LEN + qi) * DMODEL + h * 64 + d] = f32_to_bf16(o[n][j]);
    }
}

// ---------------- launch ----------------
extern "C" void kernel_launch(void* const* d_in, const int* in_sizes, int n_in,
                              void* d_out, int out_size, void* d_ws, size_t ws_size,
                              hipStream_t stream) {
  (void)in_sizes; (void)n_in; (void)out_size; (void)ws_size;
  const float* x     = (const float*)d_in[0];
  const float* alpha = (const float*)d_in[1];
  const float* Wq    = (const float*)d_in[2];
  const float* bq    = (const float*)d_in[3];
  const float* Wk    = (const float*)d_in[4];
  const float* bk    = (const float*)d_in[5];
  const float* Wv    = (const float*)d_in[6];
  const float* bv    = (const float*)d_in[7];
  const float* W_o   = (const float*)d_in[8];
  const float* Wfc   = (const float*)d_in[9];
  const float* bfc   = (const float*)d_in[10];

  char* ws = (char*)d_ws;
  int* halfw  = (int*)ws;
  u16* xb     = (u16*)(ws + 256);
  u16* Wqkv_t = xb + (size_t)MROWS * DMODEL;
  u16* qkv    = Wqkv_t + (size_t)3 * DMODEL * DMODEL;   // [4096][3072]
  u16* ao     = qkv + (size_t)MROWS * QKV_LD;
  u16* Wc_t   = ao + (size_t)MROWS * DMODEL;

  hipLaunchKernelGGL(win_kernel, dim3(1), dim3(256), 0, stream, x, alpha, halfw);
  hipLaunchKernelGGL(conv_x_bf16, dim3(MROWS * DMODEL / (256 * 8)), dim3(256), 0, stream, x, xb);
  hipLaunchKernelGGL(transpose_qkv, dim3(32, 32, 3), dim3(32, 8), 0, stream, Wq, Wk, Wv, Wqkv_t);
  hipLaunchKernelGGL(build_wc, dim3(8, 16), dim3(128), 0, stream, W_o, Wfc, Wc_t);
  hipLaunchKernelGGL(gemm_qkv, dim3(256), dim3(512), 0, stream,
                     xb, Wqkv_t, bq, bk, bv, qkv);
  hipLaunchKernelGGL(attn_win, dim3(S_LEN / 64, NHEAD, BATCH), dim3(256), 0, stream,
                     qkv, ao, halfw);
  hipLaunchKernelGGL((gemm_bt<0>), dim3(32, 8), dim3(256), 0, stream,
                     ao, Wc_t, bfc, bfc, bfc, d_out, d_out, d_out, DMODEL);
}

// Round 3
// 104.549 us; speedup vs baseline: 1.2187x; 1.1309x over previous
//
#include <hip/hip_runtime.h>
#include <hip/hip_bf16.h>
#include <stdint.h>
#include <stddef.h>

#define S_LEN 2048
#define DMODEL 1024
#define NHEAD 16
#define HDIM 64
#define BATCH 2
#define MROWS (BATCH * S_LEN) /* 4096 */
#define QKV_LD 3072

typedef unsigned short u16;
typedef __attribute__((ext_vector_type(8))) short bf16x8;
typedef __attribute__((ext_vector_type(4))) float f32x4;

__device__ inline u16 f32_to_bf16(float f) {
  union { float f; unsigned int u; } v; v.f = f;
  unsigned int u = v.u;
  unsigned int r = (u + 0x7fffu + ((u >> 16) & 1u)) >> 16;
  return (u16)r;
}

__device__ inline void gload16(const u16* g, u16* l) {
  __builtin_amdgcn_global_load_lds(
      (const __attribute__((address_space(1))) unsigned int*)g,
      (__attribute__((address_space(3))) unsigned int*)l, 16, 0, 0);
}

// ---------------- x -> bf16 (+ fused window computation in last block) ----------------
__global__ __launch_bounds__(256) void conv_x_bf16(const float* __restrict__ x,
                                                   u16* __restrict__ xb,
                                                   const float* __restrict__ alpha,
                                                   int* __restrict__ halfw) {
  if (blockIdx.x == 2048) {
    // window-size computation (1 block)
    __shared__ float red[4];
    int tid = threadIdx.x;
    float s = 0.f;
    for (int i = tid; i < BATCH * DMODEL; i += 256) {
      int b = i >> 10, d = i & 1023;
      size_t base = (size_t)b * S_LEN * DMODEL + d;
      float f1 = x[base + (size_t)(S_LEN - 1) * DMODEL];
      float f0 = x[base + (size_t)(S_LEN - 2) * DMODEL];
      s += fabsf(f1 - f0);
    }
#pragma unroll
    for (int m = 32; m >= 1; m >>= 1) s += __shfl_xor(s, m, 64);
    if ((tid & 63) == 0) red[tid >> 6] = s;
    __syncthreads();
    if (tid == 0) {
      float total = red[0] + red[1] + red[2] + red[3];
      float mean = total / (float)(BATCH * DMODEL);
      float e1 = x[(size_t)(S_LEN - 1) * DMODEL];
      float e0 = x[(size_t)(S_LEN - 2) * DMODEL];
      float ew = fabsf(e1 - e0);
      float a = 1.f / (1.f + expf(-alpha[0]));
      float sig = a * mean + (1.f - a) * ew;
      float scale = 1.f / (1.f + expf(-sig));
      int wv = (int)floorf(24.f + 96.f * scale);
      *halfw = wv >> 1;
    }
    return;
  }
  size_t i = ((size_t)blockIdx.x * 256 + threadIdx.x) * 8;
  float4 v0 = *(const float4*)(x + i);
  float4 v1 = *(const float4*)(x + i + 4);
  bf16x8 r;
  r[0] = (short)f32_to_bf16(v0.x); r[1] = (short)f32_to_bf16(v0.y);
  r[2] = (short)f32_to_bf16(v0.z); r[3] = (short)f32_to_bf16(v0.w);
  r[4] = (short)f32_to_bf16(v1.x); r[5] = (short)f32_to_bf16(v1.y);
  r[6] = (short)f32_to_bf16(v1.z); r[7] = (short)f32_to_bf16(v1.w);
  *(bf16x8*)(xb + i) = r;
}

// ---------------- transpose Wq/Wk/Wv -> bf16 [3][N][K] ----------------
__global__ __launch_bounds__(256) void transpose_qkv(const float* __restrict__ Wq,
                                                     const float* __restrict__ Wk,
                                                     const float* __restrict__ Wv,
                                                     u16* __restrict__ Wt) {
  __shared__ float tile[32][33];
  const float* W = blockIdx.z == 0 ? Wq : (blockIdx.z == 1 ? Wk : Wv);
  int k0 = blockIdx.x * 32, n0 = blockIdx.y * 32;
  int tx = threadIdx.x, ty = threadIdx.y; // (32, 8)
#pragma unroll
  for (int i = 0; i < 4; ++i)
    tile[ty + i * 8][tx] = W[(size_t)(k0 + ty + i * 8) * DMODEL + n0 + tx];
  __syncthreads();
  u16* o = Wt + (size_t)blockIdx.z * DMODEL * DMODEL;
#pragma unroll
  for (int i = 0; i < 4; ++i)
    o[(size_t)(n0 + ty + i * 8) * DMODEL + k0 + tx] = f32_to_bf16(tile[tx][ty + i * 8]);
}

// ---------------- Wc = blockdiag(W_o) @ Wfc, stored transposed bf16 [N][K] ----------------
__global__ __launch_bounds__(128) void build_wc(const float* __restrict__ W_o,
                                                const float* __restrict__ Wfc,
                                                u16* __restrict__ Wc_t) {
  __shared__ float lds[64 * 128];
  int nb = blockIdx.x, h = blockIdx.y, tx = threadIdx.x;
  int n0 = nb * 128;
#pragma unroll
  for (int c = 0; c < 64; ++c)
    lds[c * 128 + tx] = Wfc[(size_t)(h * 64 + c) * DMODEL + n0 + tx];
  __syncthreads();
  float acc[64];
#pragma unroll
  for (int d = 0; d < 64; ++d) acc[d] = 0.f;
  for (int c = 0; c < 64; ++c) {
    float wv = lds[c * 128 + tx];
#pragma unroll
    for (int d = 0; d < 64; ++d)
      acc[d] += W_o[(size_t)(h * 64 + d) * 64 + c] * wv;
  }
  u16 tmp[64];
#pragma unroll
  for (int d = 0; d < 64; ++d) tmp[d] = f32_to_bf16(acc[d]);
  u16* dst = Wc_t + (size_t)(n0 + tx) * DMODEL + h * 64;
#pragma unroll
  for (int q = 0; q < 8; ++q)
    *(bf16x8*)(dst + q * 8) = *(bf16x8*)(tmp + q * 8);
}

// ---------------- QKV GEMM: 256x192 tile, BK=64, 8 waves, dbuf 2-phase ----------------
#define G1_BM 256
#define G1_BN 192
#define G1_ASZ (G1_BM * 64) /* u16 elems */
#define G1_BSZ (G1_BN * 64)
__global__ __launch_bounds__(512, 2) void gemm_qkv(
    const u16* __restrict__ A, const u16* __restrict__ Bt,
    const float* __restrict__ bq, const float* __restrict__ bk,
    const float* __restrict__ bv, u16* __restrict__ out) {
  __shared__ __align__(16) u16 smem[2][G1_ASZ + G1_BSZ]; // 2 x 56 KiB

  const int tid = threadIdx.x;
  const int l = tid & 63, w = tid >> 6;   // 8 waves
  const int wr = w >> 2, wc = w & 3;      // 2 x 4 wave grid; wave tile 128x48
  const int lrow = l & 15, lk = l >> 4;

  // bn-major bijective XCD swizzle: each XCD owns 2 bn-tiles x 16 bm-tiles
  // -> per-XCD B slice = 2*192 cols * 2KB = 768KB, L2-resident across bm sweep.
  const int xcd = blockIdx.x & 7;
  const int idx = blockIdx.x >> 3;        // 0..31
  const int bm = idx & 15;
  const int bn = xcd * 2 + (idx >> 4);
  const int rowA0 = bm * G1_BM;
  const int colB0 = bn * G1_BN;

  f32x4 acc[8][3] = {};

  auto stage = [&](int buf, int kt) {
    u16* As = smem[buf];
    u16* Bs = smem[buf] + G1_ASZ;
#pragma unroll
    for (int i = 0; i < 4; ++i) {
      int c = i * 512 + tid;
      int row = c >> 3, u = c & 7;
      const u16* g = A + (size_t)(rowA0 + row) * DMODEL + kt + ((u ^ (row & 7)) << 3);
      gload16(g, As + c * 8);
    }
#pragma unroll
    for (int i = 0; i < 3; ++i) {
      int c = i * 512 + tid;
      int row = c >> 3, u = c & 7;
      const u16* g = Bt + (size_t)(colB0 + row) * DMODEL + kt + ((u ^ (row & 7)) << 3);
      gload16(g, Bs + c * 8);
    }
  };

  stage(0, 0);
  asm volatile("s_waitcnt vmcnt(0)");
  __syncthreads();

  int buf = 0;
#pragma unroll 1
  for (int t = 0; t < 16; ++t) {
    if (t < 15) stage(buf ^ 1, (t + 1) * 64);
    const u16* As = smem[buf];
    const u16* Bs = smem[buf] + G1_ASZ;
#pragma unroll
    for (int kk = 0; kk < 2; ++kk) {
      bf16x8 af[8], bg[3];
      const int ksw = ((kk << 2) + lk);
#pragma unroll
      for (int m = 0; m < 8; ++m) {
        int r = wr * 128 + m * 16 + lrow;
        af[m] = *(const bf16x8*)(As + r * 64 + ((ksw ^ (lrow & 7)) << 3));
      }
#pragma unroll
      for (int n = 0; n < 3; ++n) {
        int r = wc * 48 + n * 16 + lrow;
        bg[n] = *(const bf16x8*)(Bs + r * 64 + ((ksw ^ (lrow & 7)) << 3));
      }
#pragma unroll
      for (int m = 0; m < 8; ++m)
#pragma unroll
        for (int n = 0; n < 3; ++n)
          acc[m][n] = __builtin_amdgcn_mfma_f32_16x16x32_bf16(af[m], bg[n], acc[m][n], 0, 0, 0);
    }
    if (t < 15) {
      asm volatile("s_waitcnt vmcnt(0)");
      __syncthreads();
      buf ^= 1;
    }
  }

  // epilogue: per-column bias; q columns also get *0.125 scale fold
#pragma unroll
  for (int n = 0; n < 3; ++n) {
    int c = colB0 + wc * 48 + n * 16 + lrow;   // 0..3071
    float bias = (c < 1024) ? bq[c] : ((c < 2048) ? bk[c - 1024] : bv[c - 2048]);
    float mult = (c < 1024) ? 0.125f : 1.0f;
#pragma unroll
    for (int m = 0; m < 8; ++m) {
      int r0 = rowA0 + wr * 128 + m * 16 + lk * 4;
#pragma unroll
      for (int j = 0; j < 4; ++j)
        out[(size_t)(r0 + j) * QKV_LD + c] = f32_to_bf16((acc[m][n][j] + bias) * mult);
    }
  }
}

// ---------------- final FC GEMM: 128x128 tile, BK=64, 4 waves, dbuf 2-phase ----------------
// out[4096][1024] (f32) = ao[4096][1024] @ Wc_t[1024][1024]^T + bfc
__global__ __launch_bounds__(256) void gemm_fc(const u16* __restrict__ A,
                                               const u16* __restrict__ Bt,
                                               const float* __restrict__ bias,
                                               float* __restrict__ out) {
  __shared__ __align__(16) u16 smem[2][256 * 64]; // 2 x 32 KiB (A 8192 + B 8192)

  const int tid = threadIdx.x;
  const int l = tid & 63, w = tid >> 6;   // 4 waves, 2x2
  const int wr = w >> 1, wc = w & 1;
  const int lrow = l & 15, lk = l >> 4;

  // bn-major XCD swizzle: grid 256 = 32 bm x 8 bn; each XCD owns 1 bn x 32 bm
  const int bn = blockIdx.x & 7;
  const int bm = blockIdx.x >> 3;
  const int rowA0 = bm * 128, colB0 = bn * 128;

  f32x4 acc[4][4] = {};

  auto stage = [&](int buf, int kt) {
    u16* As = smem[buf];
    u16* Bs = smem[buf] + 128 * 64;
#pragma unroll
    for (int i = 0; i < 4; ++i) {
      int c = i * 256 + tid;
      int row = c >> 3, u = c & 7;
      const u16* g = A + (size_t)(rowA0 + row) * DMODEL + kt + ((u ^ (row & 7)) << 3);
      gload16(g, As + c * 8);
    }
#pragma unroll
    for (int i = 0; i < 4; ++i) {
      int c = i * 256 + tid;
      int row = c >> 3, u = c & 7;
      const u16* g = Bt + (size_t)(colB0 + row) * DMODEL + kt + ((u ^ (row & 7)) << 3);
      gload16(g, Bs + c * 8);
    }
  };

  stage(0, 0);
  asm volatile("s_waitcnt vmcnt(0)");
  __syncthreads();

  int buf = 0;
#pragma unroll 1
  for (int t = 0; t < 16; ++t) {
    if (t < 15) stage(buf ^ 1, (t + 1) * 64);
    const u16* As = smem[buf];
    const u16* Bs = smem[buf] + 128 * 64;
#pragma unroll
    for (int kk = 0; kk < 2; ++kk) {
      bf16x8 af[4], bg[4];
      const int ksw = ((kk << 2) + lk);
#pragma unroll
      for (int m = 0; m < 4; ++m) {
        int r = wr * 64 + m * 16 + lrow;
        af[m] = *(const bf16x8*)(As + r * 64 + ((ksw ^ (lrow & 7)) << 3));
      }
#pragma unroll
      for (int n = 0; n < 4; ++n) {
        int r = wc * 64 + n * 16 + lrow;
        bg[n] = *(const bf16x8*)(Bs + r * 64 + ((ksw ^ (lrow & 7)) << 3));
      }
#pragma unroll
      for (int m = 0; m < 4; ++m)
#pragma unroll
        for (int n = 0; n < 4; ++n)
          acc[m][n] = __builtin_amdgcn_mfma_f32_16x16x32_bf16(af[m], bg[n], acc[m][n], 0, 0, 0);
    }
    if (t < 15) {
      asm volatile("s_waitcnt vmcnt(0)");
      __syncthreads();
      buf ^= 1;
    }
  }

#pragma unroll
  for (int n = 0; n < 4; ++n) {
    int c = colB0 + wc * 64 + n * 16 + lrow;
    float bv = bias[c];
#pragma unroll
    for (int m = 0; m < 4; ++m) {
      int r0 = rowA0 + wr * 64 + m * 16 + lk * 4;
#pragma unroll
      for (int j = 0; j < 4; ++j)
        out[(size_t)(r0 + j) * DMODEL + c] = acc[m][n][j] + bv;
    }
  }
}

// ---------------- banded attention: 64 queries x 192 keys per block ----------------
__global__ __launch_bounds__(256) void attn_win(const u16* __restrict__ qkv,
                                                u16* __restrict__ ao,
                                                const int* __restrict__ halfptr) {
  __shared__ __align__(16) u16 KP[12800];  // K [192][64] swizzled; reused as P [64][200]
  __shared__ __align__(16) u16 Vt[64 * 200]; // V transposed [d][key]
  const int tid = threadIdx.x, l = tid & 63, w = tid >> 6;
  const int lrow = l & 15, lk = l >> 4;
  const int q0 = blockIdx.x * 64, k0 = q0 - 64;
  const int h = blockIdx.y, b = blockIdx.z;
  const int halfw = *halfptr;

  const u16* qb = qkv;
  const u16* kb = qkv + 1024;
  const u16* vb = qkv + 2048;

  // --- K stage: global_load_lds, pre-swizzled source, linear dest.
  // No bounds check: out-of-band rows land in valid ws memory (finite garbage)
  // and are always masked below.
#pragma unroll
  for (int i = 0; i < 6; ++i) {
    int c = i * 256 + tid;        // 0..1535
    int row = c >> 3, u = c & 7;  // row 0..191
    const u16* g = kb + (ptrdiff_t)((b * S_LEN + k0 + row) * QKV_LD + h * 64 + ((u ^ (row & 7)) << 3));
    gload16(g, KP + c * 8);
  }
  // --- Q fragments (q pre-scaled by 1/8 in gemm_qkv)
  const int qrow = q0 + w * 16 + lrow;
  bf16x8 qf[2];
#pragma unroll
  for (int kk = 0; kk < 2; ++kk)
    qf[kk] = *(const bf16x8*)(qb + (ptrdiff_t)((b * S_LEN + qrow) * QKV_LD + h * 64 + kk * 32 + lk * 8));
  // --- V into registers (transpose-write deferred until after QK^T)
  bf16x8 vreg[6];
#pragma unroll
  for (int i = 0; i < 6; ++i) {
    int c = i * 256 + tid;
    int row = c % 192, ch = c / 192;
    vreg[i] = *(const bf16x8*)(vb + (ptrdiff_t)((b * S_LEN + k0 + row) * QKV_LD + h * 64 + ch * 8));
  }

  asm volatile("s_waitcnt vmcnt(0)" ::: "memory");
  __syncthreads();

  // --- QK^T: 16 x 192 per wave
  f32x4 sc[12];
#pragma unroll
  for (int f = 0; f < 12; ++f) sc[f] = (f32x4){0.f, 0.f, 0.f, 0.f};
#pragma unroll
  for (int kk = 0; kk < 2; ++kk) {
#pragma unroll
    for (int f = 0; f < 12; ++f) {
      bf16x8 kf = *(const bf16x8*)(KP + (f * 16 + lrow) * 64 + ((((kk << 2) + lk) ^ (lrow & 7)) << 3));
      sc[f] = __builtin_amdgcn_mfma_f32_16x16x32_bf16(qf[kk], kf, sc[f], 0, 0, 0);
    }
  }

  // --- V transpose writes (overlap with other waves' MFMA)
#pragma unroll
  for (int i = 0; i < 6; ++i) {
    int c = i * 256 + tid;
    int row = c % 192, ch = c / 192;
#pragma unroll
    for (int e = 0; e < 8; ++e)
      Vt[(ch * 8 + e) * 200 + row] = (u16)vreg[i][e];
  }

  // --- mask + softmax
  float rmax[4] = {-3e38f, -3e38f, -3e38f, -3e38f};
  const int qbase = q0 + w * 16 + lk * 4;
#pragma unroll
  for (int f = 0; f < 12; ++f) {
    int kj = k0 + f * 16 + lrow;
    bool kok = (kj >= 0) && (kj < S_LEN);
#pragma unroll
    for (int j = 0; j < 4; ++j) {
      int qi = qbase + j;
      float v = sc[f][j];
      int dd = qi - kj;
      int ad = dd < 0 ? -dd : dd;
      v = (kok && ad <= halfw) ? v : -1e30f;
      sc[f][j] = v;
      rmax[j] = fmaxf(rmax[j], v);
    }
  }
#pragma unroll
  for (int j = 0; j < 4; ++j) {
    rmax[j] = fmaxf(rmax[j], __shfl_xor(rmax[j], 1, 16));
    rmax[j] = fmaxf(rmax[j], __shfl_xor(rmax[j], 2, 16));
    rmax[j] = fmaxf(rmax[j], __shfl_xor(rmax[j], 4, 16));
    rmax[j] = fmaxf(rmax[j], __shfl_xor(rmax[j], 8, 16));
  }
  float rsum[4] = {0.f, 0.f, 0.f, 0.f};
#pragma unroll
  for (int f = 0; f < 12; ++f)
#pragma unroll
    for (int j = 0; j < 4; ++j) {
      float e = __expf(sc[f][j] - rmax[j]);
      sc[f][j] = e;
      rsum[j] += e;
    }
#pragma unroll
  for (int j = 0; j < 4; ++j) {
    rsum[j] += __shfl_xor(rsum[j], 1, 16);
    rsum[j] += __shfl_xor(rsum[j], 2, 16);
    rsum[j] += __shfl_xor(rsum[j], 4, 16);
    rsum[j] += __shfl_xor(rsum[j], 8, 16);
  }
  float rinv[4];
#pragma unroll
  for (int j = 0; j < 4; ++j) rinv[j] = 1.0f / rsum[j];

  __syncthreads(); // all K-LDS reads + all Vt writes complete

  u16* Ps = KP; // P tile [64][200]
#pragma unroll
  for (int f = 0; f < 12; ++f)
#pragma unroll
    for (int j = 0; j < 4; ++j) {
      int prow = w * 16 + lk * 4 + j;
      Ps[prow * 200 + f * 16 + lrow] = f32_to_bf16(sc[f][j] * rinv[j]);
    }
  __syncthreads();

  // --- P @ V : 16 x 64 per wave
  f32x4 o[4] = {};
#pragma unroll
  for (int jt = 0; jt < 6; ++jt) {
    bf16x8 pa = *(const bf16x8*)(Ps + (w * 16 + lrow) * 200 + jt * 32 + lk * 8);
#pragma unroll
    for (int n = 0; n < 4; ++n) {
      bf16x8 vf = *(const bf16x8*)(Vt + (n * 16 + lrow) * 200 + jt * 32 + lk * 8);
      o[n] = __builtin_amdgcn_mfma_f32_16x16x32_bf16(pa, vf, o[n], 0, 0, 0);
    }
  }
#pragma unroll
  for (int n = 0; n < 4; ++n)
#pragma unroll
    for (int j = 0; j < 4; ++j) {
      int qi = q0 + w * 16 + lk * 4 + j;
      int d = n * 16 + lrow;
      ao[(size_t)(b * S_LEN + qi) * DMODEL + h * 64 + d] = f32_to_bf16(o[n][j]);
    }
}

// ---------------- launch ----------------
extern "C" void kernel_launch(void* const* d_in, const int* in_sizes, int n_in,
                              void* d_out, int out_size, void* d_ws, size_t ws_size,
                              hipStream_t stream) {
  (void)in_sizes; (void)n_in; (void)out_size; (void)ws_size;
  const float* x     = (const float*)d_in[0];
  const float* alpha = (const float*)d_in[1];
  const float* Wq    = (const float*)d_in[2];
  const float* bq    = (const float*)d_in[3];
  const float* Wk    = (const float*)d_in[4];
  const float* bk    = (const float*)d_in[5];
  const float* Wv    = (const float*)d_in[6];
  const float* bv    = (const float*)d_in[7];
  const float* W_o   = (const float*)d_in[8];
  const float* Wfc   = (const float*)d_in[9];
  const float* bfc   = (const float*)d_in[10];

  char* ws = (char*)d_ws;
  int* halfw  = (int*)ws;
  u16* xb     = (u16*)(ws + 256);
  u16* Wqkv_t = xb + (size_t)MROWS * DMODEL;
  u16* qkv    = Wqkv_t + (size_t)3 * DMODEL * DMODEL;   // [4096][3072]
  u16* ao     = qkv + (size_t)MROWS * QKV_LD;
  u16* Wc_t   = ao + (size_t)MROWS * DMODEL;

  hipLaunchKernelGGL(conv_x_bf16, dim3(MROWS * DMODEL / (256 * 8) + 1), dim3(256), 0, stream,
                     x, xb, alpha, halfw);
  hipLaunchKernelGGL(transpose_qkv, dim3(32, 32, 3), dim3(32, 8), 0, stream, Wq, Wk, Wv, Wqkv_t);
  hipLaunchKernelGGL(build_wc, dim3(8, 16), dim3(128), 0, stream, W_o, Wfc, Wc_t);
  hipLaunchKernelGGL(gemm_qkv, dim3(256), dim3(512), 0, stream,
                     xb, Wqkv_t, bq, bk, bv, qkv);
  hipLaunchKernelGGL(attn_win, dim3(S_LEN / 64, NHEAD, BATCH), dim3(256), 0, stream,
                     qkv, ao, halfw);
  hipLaunchKernelGGL(gemm_fc, dim3(256), dim3(256), 0, stream,
                     ao, Wc_t, bfc, (float*)d_out);
}